// Round 13
// baseline (164.586 us; speedup 1.0000x reference)
//
#include <hip/hip_runtime.h>

// Conv2D 3x3 VALID NHWC, B=16 H=W=224 C=32 F=32 -> [16,222,222,32] fp32.
// im2col GEMM M=788544 K=288 N=32, bf16 MFMA 16x16x32 (swapped: D[filt][pix]).
// Round 13: NO LDS, NO BARRIERS. R8/R9/R12 all land ~50-55us with every pipe
// <30% busy -- the staged producer/consumer structure itself caps fabric
// efficiency. Direct global->reg MFMA fragments: wave loads 2 KB/tap
// coalesced, L1 serves kw-overlap (3 taps share lines), per-XCD L2 serves
// kh-overlap. R0's 9.4x FETCH blowup was linear-grid round-robin putting
// vertical neighbors on different XCDs; fixed with a bijective XCD-chunked
// work remap (each XCD owns ~2 whole batches -> all vertical reuse in its
// private L2). Wave sweeps 4 consecutive chunks to amortize weight setup.

#define HO 222
#define WO 222
#define HIN 224
#define WIN 224
#define CIN 32
#define FOUT 32
#define CKROW 14                    // 16-px chunks per output row (13 full + 1 partial)
#define CPERB (HO * CKROW)          // 3108 chunks per batch image
#define NCHUNKS (16 * CPERB)        // 49728
#define CPW 4                       // chunks per wave (consecutive along rows)
#define NBLK (NCHUNKS / (4 * CPW))  // 3108 blocks of 4 waves

typedef __attribute__((ext_vector_type(8))) short short8;
typedef __attribute__((ext_vector_type(4))) float float4v;

__device__ inline short f2bf(float f) {                  // RNE (weights only)
    unsigned u = __builtin_bit_cast(unsigned, f);
    unsigned r = (u + 0x7FFFu + ((u >> 16) & 1u)) >> 16;
    return (short)r;
}

__global__ __launch_bounds__(256) void conv3x3_direct(
    const float* __restrict__ x,     // [16,224,224,32]
    const float* __restrict__ w,     // [32][288 = (kh,kw,c)]
    const float* __restrict__ bias,  // [32]
    float* __restrict__ out)         // [16,222,222,32]
{
    const int tid  = threadIdx.x;
    const int lane = tid & 63;
    const int wave = tid >> 6;             // 0..3

    const int fcol = lane & 15;            // A row (filter) / D col (pixel)
    const int kq   = lane >> 4;            // k-slice: channels kq*8 .. +7

    // ---- weights -> register A-fragments (L2-hot, identical across waves) ----
    short8 bfr[2][9];
#pragma unroll
    for (int h = 0; h < 2; ++h) {
        const float* wf = w + (h * 16 + fcol) * 288 + kq * 8;
#pragma unroll
        for (int s = 0; s < 9; ++s) {
            float4 lo = reinterpret_cast<const float4*>(wf + s * 32)[0];
            float4 hi = reinterpret_cast<const float4*>(wf + s * 32)[1];
            short8 v;
            v[0] = f2bf(lo.x); v[1] = f2bf(lo.y); v[2] = f2bf(lo.z); v[3] = f2bf(lo.w);
            v[4] = f2bf(hi.x); v[5] = f2bf(hi.y); v[6] = f2bf(hi.z); v[7] = f2bf(hi.w);
            bfr[h][s] = v;
        }
    }
    const float4 bias0 = reinterpret_cast<const float4*>(bias)[kq];      // filters kq*4..+3
    const float4 bias1 = reinterpret_cast<const float4*>(bias)[4 + kq];  // filters 16+kq*4..+3

    // ---- bijective XCD-chunked work remap (m204): dispatch XCD = bid % 8;
    //      give each XCD a CONTIGUOUS band of work ids -> each XCD owns ~2
    //      whole batches; vertical (kh) reuse stays inside its private L2. ----
    // NBLK = 3108 = 8*388 + 4
    const int bid = blockIdx.x;
    const int xcd = bid & 7;
    const int idx = bid >> 3;
    const int wrk = (xcd < 4 ? xcd * 389 : 4 * 389 + (xcd - 4) * 388) + idx;

    const int cid0 = (wrk * 4 + wave) * CPW;   // first of 4 consecutive chunks

#pragma unroll 1
    for (int i = 0; i < CPW; ++i) {
        const int cid = cid0 + i;              // < 49728 always
        const int b   = cid / CPERB;
        const int rr  = cid - b * CPERB;
        const int ho  = rr / CKROW;
        const int ck  = rr - ho * CKROW;
        const int wo  = ck * 16 + fcol;        // this lane's output pixel
        const int woc = wo < WO ? wo : WO - 1; // clamp loads; store guarded

        const float* xb = x + ((b * HIN + ho) * WIN + woc) * CIN + kq * 8;

        float4v acc0 = {0.f, 0.f, 0.f, 0.f};
        float4v acc1 = {0.f, 0.f, 0.f, 0.f};
#pragma unroll
        for (int s = 0; s < 9; ++s) {
            const int kh = s / 3, kw = s % 3;
            const float4* p = reinterpret_cast<const float4*>(xb + (kh * WIN + kw) * CIN);
            float4 lo = p[0];                  // ch kq*8   .. +3
            float4 hi = p[1];                  // ch kq*8+4 .. +7
            uint4 u0 = __builtin_bit_cast(uint4, lo);
            uint4 u1 = __builtin_bit_cast(uint4, hi);
            unsigned w0 = __builtin_amdgcn_perm(u0.y, u0.x, 0x07060302u);
            unsigned w1 = __builtin_amdgcn_perm(u0.w, u0.z, 0x07060302u);
            unsigned w2 = __builtin_amdgcn_perm(u1.y, u1.x, 0x07060302u);
            unsigned w3 = __builtin_amdgcn_perm(u1.w, u1.z, 0x07060302u);
            uint4 pk = {w0, w1, w2, w3};
            short8 a = __builtin_bit_cast(short8, pk);
            acc0 = __builtin_amdgcn_mfma_f32_16x16x32_bf16(bfr[0][s], a, acc0, 0, 0, 0);
            acc1 = __builtin_amdgcn_mfma_f32_16x16x32_bf16(bfr[1][s], a, acc1, 0, 0, 0);
        }

        // D[filter][pixel]: col(lane&15)=pixel, row=kq*4+r=filter
        if (wo < WO) {
            float* o = out + ((b * HO + ho) * WO + wo) * FOUT;
            float4 v0 = {acc0[0] + bias0.x, acc0[1] + bias0.y,
                         acc0[2] + bias0.z, acc0[3] + bias0.w};
            float4 v1 = {acc1[0] + bias1.x, acc1[1] + bias1.y,
                         acc1[2] + bias1.z, acc1[3] + bias1.w};
            reinterpret_cast<float4*>(o)[kq]     = v0;   // filters kq*4..+3
            reinterpret_cast<float4*>(o)[4 + kq] = v1;   // filters 16+kq*4..+3
        }
    }
}

extern "C" void kernel_launch(void* const* d_in, const int* in_sizes, int n_in,
                              void* d_out, int out_size, void* d_ws, size_t ws_size,
                              hipStream_t stream) {
    const float* x    = (const float*)d_in[0];
    const float* w    = (const float*)d_in[1];
    const float* bias = (const float*)d_in[2];
    float* out        = (float*)d_out;

    conv3x3_direct<<<dim3(NBLK), dim3(256), 0, stream>>>(x, w, bias, out);
}

// Round 14
// 45.585 us; speedup vs baseline: 3.6105x; 3.6105x over previous
//
#include <hip/hip_runtime.h>

// Conv2D 3x3 VALID NHWC, B=16 H=W=224 C=32 F=32 -> [16,222,222,32] fp32.
// Round 14: wave-autonomous strips -- LDS staging WITHOUT barriers.
// 13-round synthesis: barriered LDS structures plateau 50-55us with all pipes
// <30% (lockstep + bursty streams); no-LDS direct is latency-bound (R13,
// 176us, but FETCH 50MB proved XCD remap + L2 serve the 9x reuse).
// Here: 2048 waves each own a 64x7 output strip with a PRIVATE 4-row bf16
// LDS ring. Per output row r: load row r+3 to regs | compute row r (MFMA
// from ring) | perm-pack + ds_write row r+3. No s_barrier in the kernel;
// in-wave program order + compiler waitcnts are the only sync. 64B/px
// unpadded rows: bank-arithmetic-verified conflict-free for BOTH the b128
// fragment read (16(px&1)+4kq+j partitions: 8 words/bank = min) and the
// b64 stage write (4/bank = min); b128 stays 16B-aligned; 135 KB LDS.

#define HO 222
#define WO 222
#define HIN 224
#define WIN 224
#define CIN 32
#define FOUT 32

#define RPW 7                 // output rows per wave-strip (32 strips x 7 >= 222)
#define WROWB 4224            // 66 px * 64 B bf16 (unpadded -- conflict-free)
#define WAVELDS 16896         // 4 ring slots
#define NSG 9                 // stage granule-iters per lane (528/64 -> 9)

typedef __attribute__((ext_vector_type(8))) short short8;
typedef __attribute__((ext_vector_type(4))) float float4v;

__device__ inline short f2bf(float f) {                  // RNE (weights only)
    unsigned u = __builtin_bit_cast(unsigned, f);
    unsigned r = (u + 0x7FFFu + ((u >> 16) & 1u)) >> 16;
    return (short)r;
}

__global__ __launch_bounds__(512, 2) void conv3x3_wave(
    const float* __restrict__ x,     // [16,224,224,32]
    const float* __restrict__ w,     // [32][288 = (kh,kw,c)]
    const float* __restrict__ bias,  // [32]
    float* __restrict__ out)         // [16,222,222,32]
{
    __shared__ uint4 lds_all[8 * WAVELDS / 16];          // 135168 B
    const int tid  = threadIdx.x;
    const int lane = tid & 63;
    const int wave = tid >> 6;                           // 0..7
    char* wbase = reinterpret_cast<char*>(lds_all) + wave * WAVELDS;

    const int fcol = lane & 15;            // A row (filter) / D col (pixel)
    const int kq   = lane >> 4;            // k-slice: channels kq*8..+7

    // ---- weights -> register A-fragments ----
    short8 bfr[2][9];
#pragma unroll
    for (int h = 0; h < 2; ++h) {
        const float* wf = w + (h * 16 + fcol) * 288 + kq * 8;
#pragma unroll
        for (int s = 0; s < 9; ++s) {
            float4 lo = reinterpret_cast<const float4*>(wf + s * 32)[0];
            float4 hi = reinterpret_cast<const float4*>(wf + s * 32)[1];
            short8 v;
            v[0] = f2bf(lo.x); v[1] = f2bf(lo.y); v[2] = f2bf(lo.z); v[3] = f2bf(lo.w);
            v[4] = f2bf(hi.x); v[5] = f2bf(hi.y); v[6] = f2bf(hi.z); v[7] = f2bf(hi.w);
            bfr[h][s] = v;
        }
    }
    const float4 bias0 = reinterpret_cast<const float4*>(bias)[kq];
    const float4 bias1 = reinterpret_cast<const float4*>(bias)[4 + kq];

    // ---- work decode, XCD-bijective (256 = 8 x 32): each XCD owns 2 images ----
    const int bid  = blockIdx.x;
    const int sbid = (bid & 7) * 32 + (bid >> 3);
    const int W    = sbid * 8 + wave;      // 0..2047 wave-strip id
    const int b    = W >> 7;               // image (128 strips each)
    const int rem  = W & 127;
    const int cst  = rem >> 5;             // col strip 0..3
    const int rst  = rem & 31;             // row strip 0..31 (consecutive W -> vertical neighbors)
    const int c0   = cst * 64;
    const int gr0  = rst * RPW;
    const int nck  = (cst < 3) ? 4 : 2;    // strip 3 covers cols 192..221 -> 2 chunks

    float4 sv[NSG];                        // stage registers (const-indexed only)

    // stage input row gr0+RR (66 px fp32) into regs
#define SLOAD(RR)                                                             \
    {                                                                         \
        int ir_ = gr0 + (RR); if (ir_ > HIN - 1) ir_ = HIN - 1;               \
        _Pragma("unroll")                                                     \
        for (int i_ = 0; i_ < NSG; ++i_) {                                    \
            int g_ = lane + 64 * i_; if (g_ > 527) g_ = 527;                  \
            int px_ = g_ >> 3, sub_ = g_ & 7;                                 \
            int ic_ = c0 + px_; if (ic_ > WIN - 1) ic_ = WIN - 1;             \
            sv[i_] = *reinterpret_cast<const float4*>(                        \
                x + ((b * HIN + ir_) * WIN + ic_) * CIN + sub_ * 4);          \
        }                                                                     \
    }

    // pack to bf16, write into ring slot (RR)&3
#define SWRITE(RR)                                                            \
    {                                                                         \
        char* sb_ = wbase + ((RR) & 3) * WROWB;                               \
        _Pragma("unroll")                                                     \
        for (int i_ = 0; i_ < NSG; ++i_) {                                    \
            int g_ = lane + 64 * i_; if (g_ > 527) g_ = 527;                  \
            int px_ = g_ >> 3, sub_ = g_ & 7;                                 \
            uint4 u_ = __builtin_bit_cast(uint4, sv[i_]);                     \
            uint2 p_;                                                         \
            p_.x = __builtin_amdgcn_perm(u_.y, u_.x, 0x07060302u);            \
            p_.y = __builtin_amdgcn_perm(u_.w, u_.z, 0x07060302u);            \
            *reinterpret_cast<uint2*>(sb_ + px_ * 64 + sub_ * 8) = p_;        \
        }                                                                     \
    }

    // ---------- prologue: rows 0,1,2 into the ring ----------
    SLOAD(0); SWRITE(0);
    SLOAD(1); SWRITE(1);
    SLOAD(2); SWRITE(2);

    // ---------- barrier-free main loop ----------
#pragma unroll 1
    for (int r = 0; r < RPW; ++r) {
        if (r < RPW - 1) SLOAD(r + 3);               // rows 3..8, in flight over compute
        __builtin_amdgcn_sched_barrier(0);           // don't sink loads into compute

        const int ho = gr0 + r;
#pragma unroll
        for (int ck = 0; ck < 4; ++ck) {
            if (ck < nck) {
                float4v acc0 = {0.f, 0.f, 0.f, 0.f};
                float4v acc1 = {0.f, 0.f, 0.f, 0.f};
#pragma unroll
                for (int s = 0; s < 9; ++s) {
                    const int kh = s / 3, kw = s % 3;
                    const short8 a = *reinterpret_cast<const short8*>(
                        wbase + ((r + kh) & 3) * WROWB + (ck * 16 + fcol + kw) * 64 + kq * 16);
                    acc0 = __builtin_amdgcn_mfma_f32_16x16x32_bf16(bfr[0][s], a, acc0, 0, 0, 0);
                    acc1 = __builtin_amdgcn_mfma_f32_16x16x32_bf16(bfr[1][s], a, acc1, 0, 0, 0);
                }
                // D[filter][pixel]: col(lane&15)=pixel, row=kq*4+r=filter
                const int wo = c0 + ck * 16 + fcol;
                if (ho < HO && wo < WO) {
                    float* o = out + ((b * HO + ho) * WO + wo) * FOUT;
                    float4 v0 = {acc0[0] + bias0.x, acc0[1] + bias0.y,
                                 acc0[2] + bias0.z, acc0[3] + bias0.w};
                    float4 v1 = {acc1[0] + bias1.x, acc1[1] + bias1.y,
                                 acc1[2] + bias1.z, acc1[3] + bias1.w};
                    reinterpret_cast<float4*>(o)[kq]     = v0;
                    reinterpret_cast<float4*>(o)[4 + kq] = v1;
                }
            }
        }

        __builtin_amdgcn_sched_barrier(0);           // keep perms/writes after compute
        if (r < RPW - 1) SWRITE(r + 3);              // slot (r+3)&3 disjoint from read slots
    }
}

extern "C" void kernel_launch(void* const* d_in, const int* in_sizes, int n_in,
                              void* d_out, int out_size, void* d_ws, size_t ws_size,
                              hipStream_t stream) {
    const float* x    = (const float*)d_in[0];
    const float* w    = (const float*)d_in[1];
    const float* bias = (const float*)d_in[2];
    float* out        = (float*)d_out;

    conv3x3_wave<<<dim3(256), dim3(512), 0, stream>>>(x, w, bias, out);
}